// Round 2
// baseline (644.397 us; speedup 1.0000x reference)
//
#include <hip/hip_runtime.h>
#include <math.h>

// Problem constants (AdaSpatialMLP): B=128, N=196, DIM=384, K=16, H=6, R=4
#define BB  128
#define NN  196
#define CDIM 384
#define KK  16
#define HH  6
#define DR  96    // DIM/R
#define HD  64    // DIM/H

// ---------------------------------------------------------------------------
// Stage 1: mix[b,n,k,h] = softmax_k( gelu(x@W1+b1) @ W2 + b2 )
// 16 rows/block, 192 threads = 2 j-groups of 96, 8 accumulators/thread (ILP).
// LDS 36.9 KB -> 4 blocks/CU -> 12 waves/CU.
// ---------------------------------------------------------------------------
__global__ __launch_bounds__(192, 3) void adapter_kernel(
    const float* __restrict__ x,  const float* __restrict__ W1,
    const float* __restrict__ b1, const float* __restrict__ W2,
    const float* __restrict__ b2, float* __restrict__ mix_out)
{
    __shared__ float xs[16][CDIM];    // 24576 B
    __shared__ float hid[16][DR];     // 6144 B
    __shared__ float mv[16][DR + 1];  // 6208 B (pad: softmax reads stride-96)

    const int t = threadIdx.x;
    const int row0 = blockIdx.x * 16;

    // cooperative load of 16 x-rows (coalesced float4): 1536 f4 / 192 = 8 each
    {
        const float4* xg = (const float4*)(x + (size_t)row0 * CDIM);
        float4* xs4 = (float4*)(&xs[0][0]);
        #pragma unroll
        for (int i = 0; i < 8; ++i) xs4[t + 192 * i] = xg[t + 192 * i];
    }
    __syncthreads();

    const int j  = t % DR;   // output column 0..95
    const int rg = t / DR;   // 0 or 1 -> rows rg*8 .. rg*8+7

    // Layer 1 + exact GELU: hid = gelu(x @ W1 + b1), 8 rows per thread
    {
        float acc[8];
        #pragma unroll
        for (int rr = 0; rr < 8; ++rr) acc[rr] = b1[j];
        #pragma unroll 8
        for (int i = 0; i < CDIM; ++i) {
            const float w = W1[i * DR + j];           // coalesced over j, L1/L2-hot
            #pragma unroll
            for (int rr = 0; rr < 8; ++rr)
                acc[rr] += xs[rg * 8 + rr][i] * w;    // LDS broadcast
        }
        #pragma unroll
        for (int rr = 0; rr < 8; ++rr) {
            const float v = acc[rr];
            hid[rg * 8 + rr][j] = 0.5f * v * (1.0f + erff(v * 0.70710678118654752f));
        }
    }
    __syncthreads();

    // Layer 2: mv = hid @ W2 + b2
    {
        float acc[8];
        #pragma unroll
        for (int rr = 0; rr < 8; ++rr) acc[rr] = b2[j];
        #pragma unroll 8
        for (int i = 0; i < DR; ++i) {
            const float w = W2[i * DR + j];
            #pragma unroll
            for (int rr = 0; rr < 8; ++rr)
                acc[rr] += hid[rg * 8 + rr][i] * w;
        }
        #pragma unroll
        for (int rr = 0; rr < 8; ++rr) mv[rg * 8 + rr][j] = acc[rr];
    }
    __syncthreads();

    // softmax over k (stride H in mv): 96 tasks = 16 rows x 6 heads
    if (t < 96) {
        const int h = t % HH;
        const int r = t / HH;
        float mx = -1e30f;
        #pragma unroll
        for (int k = 0; k < KK; ++k) mx = fmaxf(mx, mv[r][k * HH + h]);
        float e[KK];
        float s = 0.f;
        #pragma unroll
        for (int k = 0; k < KK; ++k) { e[k] = __expf(mv[r][k * HH + h] - mx); s += e[k]; }
        const float inv = 1.0f / s;
        #pragma unroll
        for (int k = 0; k < KK; ++k) mv[r][k * HH + h] = e[k] * inv;
    }
    __syncthreads();

    // coalesced writeback (mv has padded stride -> per-element)
    {
        #pragma unroll
        for (int i = 0; i < 8; ++i) {
            const int e = t + 192 * i;       // 0..1535
            const int r = e / DR;
            const int c = e - r * DR;
            mix_out[(size_t)row0 * DR + e] = mv[r][c];
        }
    }
}

// ---------------------------------------------------------------------------
// Stage 2: out[b,m,h,c] = sum_n ( sum_k mix[b,n,k,h]*wb[k,n,m] ) * x[b,n,h*64+c]
// 1-D grid 896: b = id&127, mt = id>>7  (all 7 m-tiles of b land on the same
// XCD since 128*mt === 0 mod 8 -> x[b] fetched into one L2 once).
// Block: 384 threads = 6 waves, one head per wave. TN=14 -> LDS 36.3 KB ->
// 4 blocks/CU -> 24 waves/CU (75% occupancy ceiling).
// Per thread: acc[7 m][4 c]; A read as float2 over token pairs (ds_read_b64).
// ---------------------------------------------------------------------------
#define TN 14
#define MT 28

__global__ __launch_bounds__(384, 6) void mix_kernel(
    const float* __restrict__ x,  const float* __restrict__ mix,
    const float* __restrict__ wb, float* __restrict__ out)
{
    __shared__ float xs[TN][CDIM];     // 21504 B
    __shared__ float ms[TN][DR];       // 5376 B
    __shared__ float As[MT][HH][TN];   // 9408 B   (total 36288 B)

    const int t   = threadIdx.x;
    const int bid = blockIdx.x;
    const int b   = bid & 127;
    const int m0  = (bid >> 7) * MT;
    const int h   = t >> 6;        // wave id == head 0..5
    const int tig = t & 63;
    const int mg  = tig >> 4;      // 0..3
    const int cg  = tig & 15;      // 0..15 -> c = cg*4 (consecutive lanes -> coalesced)

    float acc[7][4];
    #pragma unroll
    for (int i = 0; i < 7; ++i)
        #pragma unroll
        for (int jj = 0; jj < 4; ++jj) acc[i][jj] = 0.f;

    for (int n0 = 0; n0 < NN; n0 += TN) {
        __syncthreads();   // previous tile fully consumed
        // stage x tile: 14 rows x 384 (coalesced float4), 1344 f4 over 384 thr
        {
            const float4* xg = (const float4*)(x + ((size_t)b * NN + n0) * CDIM);
            float4* xs4 = (float4*)(&xs[0][0]);
            for (int idx = t; idx < TN * CDIM / 4; idx += 384) xs4[idx] = xg[idx];
        }
        // stage mix tile: 14 rows x 96 (float2), 672 f2
        {
            const float2* mg2 = (const float2*)(mix + ((size_t)b * NN + n0) * DR);
            float2* ms2 = (float2*)(&ms[0][0]);
            for (int idx = t; idx < TN * DR / 2; idx += 384) ms2[idx] = mg2[idx];
        }
        __syncthreads();

        // form As[ml][hh][nl] = sum_k ms[nl][k*6+hh] * wb[k][n][m]
        for (int task = t; task < TN * MT; task += 384) {
            const int nl = task / MT;
            const int ml = task - nl * MT;
            const int n  = n0 + nl;
            const int m  = m0 + ml;
            float wv[KK];
            #pragma unroll
            for (int k = 0; k < KK; ++k)
                wv[k] = wb[((size_t)k * NN + n) * NN + m];   // coalesced over ml
            #pragma unroll
            for (int hh = 0; hh < HH; ++hh) {
                float a = 0.f;
                #pragma unroll
                for (int k = 0; k < KK; ++k)
                    a += ms[nl][k * HH + hh] * wv[k];        // LDS broadcast
                As[ml][hh][nl] = a;
            }
        }
        __syncthreads();

        // main FMA over token pairs: acc[i][j] += A[m][h][n] * x[n][h*64+cg*4+j]
        for (int np = 0; np < TN / 2; ++np) {
            float2 av[7];
            #pragma unroll
            for (int i = 0; i < 7; ++i)
                av[i] = *(const float2*)(&As[mg + 4 * i][h][2 * np]);  // ds_read_b64
            const float4 x0 = *(const float4*)(&xs[2 * np][h * HD + cg * 4]);
            const float4 x1 = *(const float4*)(&xs[2 * np + 1][h * HD + cg * 4]);
            const float xa[4] = {x0.x, x0.y, x0.z, x0.w};
            const float xb[4] = {x1.x, x1.y, x1.z, x1.w};
            #pragma unroll
            for (int i = 0; i < 7; ++i) {
                #pragma unroll
                for (int jj = 0; jj < 4; ++jj) {
                    acc[i][jj] += av[i].x * xa[jj];
                    acc[i][jj] += av[i].y * xb[jj];
                }
            }
        }
    }

    // epilogue: out[b][m][h*64 + cg*4 .. +3], one float4 per m-row per thread
    #pragma unroll
    for (int i = 0; i < 7; ++i) {
        const int m = m0 + mg + 4 * i;
        float* op = out + ((size_t)b * NN + m) * CDIM + h * HD + cg * 4;
        *(float4*)op = make_float4(acc[i][0], acc[i][1], acc[i][2], acc[i][3]);
    }
}

extern "C" void kernel_launch(void* const* d_in, const int* in_sizes, int n_in,
                              void* d_out, int out_size, void* d_ws, size_t ws_size,
                              hipStream_t stream) {
    (void)in_sizes; (void)n_in; (void)out_size; (void)ws_size;
    const float* x  = (const float*)d_in[0];
    const float* W1 = (const float*)d_in[1];
    const float* b1 = (const float*)d_in[2];
    const float* W2 = (const float*)d_in[3];
    const float* b2 = (const float*)d_in[4];
    const float* wb = (const float*)d_in[5];
    float* out = (float*)d_out;
    float* mixbuf = (float*)d_ws;   // B*N*96 floats = 9.63 MB

    adapter_kernel<<<(BB * NN) / 16, 192, 0, stream>>>(x, W1, b1, W2, b2, mixbuf);
    mix_kernel<<<(NN / MT) * BB, 384, 0, stream>>>(x, mixbuf, wb, out);
}

// Round 4
// 310.301 us; speedup vs baseline: 2.0767x; 2.0767x over previous
//
#include <hip/hip_runtime.h>
#include <math.h>

// Problem constants (AdaSpatialMLP): B=128, N=196, DIM=384, K=16, H=6, R=4
#define BB  128
#define NN  196
#define CDIM 384
#define KK  16
#define HH  6
#define DR  96    // DIM/R
#define HD  64    // DIM/H

__device__ __forceinline__ unsigned short f2bf(float f) {
    unsigned u = __float_as_uint(f);
    u += 0x7FFFu + ((u >> 16) & 1u);   // RNE
    return (unsigned short)(u >> 16);
}
__device__ __forceinline__ float bflo(unsigned u) { return __uint_as_float(u << 16); }
__device__ __forceinline__ float bfhi(unsigned u) { return __uint_as_float(u & 0xFFFF0000u); }

// ---------------------------------------------------------------------------
// Stage 1: mix[b,n,h,k] (bf16) = softmax_k( gelu(x@W1+b1) @ W2 + b2 )
// 64 rows/block (392 blocks), 192 thr = 16 rowgrp x 12 colgrp, 4x8 reg tile.
// xsT pitch 68 (272 B = 17*16): b128-aligned fragment reads for all k.
// ---------------------------------------------------------------------------
__global__ __launch_bounds__(192, 4) void adapter_kernel(
    const float* __restrict__ x,  const float* __restrict__ W1,
    const float* __restrict__ b1, const float* __restrict__ W2,
    const float* __restrict__ b2, unsigned short* __restrict__ mix_out)
{
    __shared__ float xsT[32][68];              // [k][row] 8704 B (pitch mult of 4!)
    __shared__ float wc[32][100];              // [k][col] 12800 B (W1/W2 chunks)
    __shared__ unsigned short hidT[96][68];    // [k2][row] bf16, 13056 B
    __shared__ unsigned short mv[64][100];     // bf16 logits [row][col] 12800 B

    const int t = threadIdx.x;
    const int row0 = blockIdx.x * 64;
    const int rg = t / 12;        // 0..15 -> rows 4rg..4rg+3
    const int cg = t % 12;        // 0..11 -> cols 8cg..8cg+7

    // ---- GEMM1: hid = gelu(x @ W1 + b1) ----
    float acc[4][8];
    #pragma unroll
    for (int j = 0; j < 8; ++j) {
        const float bj = b1[8 * cg + j];
        #pragma unroll
        for (int r = 0; r < 4; ++r) acc[r][j] = bj;
    }
    for (int kc = 0; kc < CDIM; kc += 32) {
        // stage x chunk transposed: [64 rows][32 k] -> xsT[k][row]
        for (int idx = t; idx < 512; idx += 192) {
            const int row = idx >> 3, kq = idx & 7;
            const float4 v = *(const float4*)(x + (size_t)(row0 + row) * CDIM + kc + 4 * kq);
            xsT[4 * kq + 0][row] = v.x; xsT[4 * kq + 1][row] = v.y;
            xsT[4 * kq + 2][row] = v.z; xsT[4 * kq + 3][row] = v.w;
        }
        // stage W1 chunk: rows kc..kc+31
        for (int idx = t; idx < 768; idx += 192) {
            const int k = idx / 24, cq = idx % 24;
            *(float4*)&wc[k][4 * cq] = *(const float4*)(W1 + (size_t)(kc + k) * DR + 4 * cq);
        }
        __syncthreads();
        #pragma unroll 4
        for (int k = 0; k < 32; ++k) {
            const float4 xv = *(const float4*)&xsT[k][4 * rg];
            const float4 w0 = *(const float4*)&wc[k][8 * cg];
            const float4 w1 = *(const float4*)&wc[k][8 * cg + 4];
            const float xr[4] = {xv.x, xv.y, xv.z, xv.w};
            const float wr[8] = {w0.x, w0.y, w0.z, w0.w, w1.x, w1.y, w1.z, w1.w};
            #pragma unroll
            for (int r = 0; r < 4; ++r)
                #pragma unroll
                for (int j = 0; j < 8; ++j) acc[r][j] += xr[r] * wr[j];
        }
        __syncthreads();
    }
    // GELU (exact) -> hidT bf16 [k2][row]
    #pragma unroll
    for (int j = 0; j < 8; ++j) {
        unsigned short g[4];
        #pragma unroll
        for (int r = 0; r < 4; ++r) {
            const float v = acc[r][j];
            g[r] = f2bf(0.5f * v * (1.0f + erff(v * 0.70710678118654752f)));
        }
        *(unsigned*)&hidT[8 * cg + j][4 * rg]     = (unsigned)g[0] | ((unsigned)g[1] << 16);
        *(unsigned*)&hidT[8 * cg + j][4 * rg + 2] = (unsigned)g[2] | ((unsigned)g[3] << 16);
    }
    __syncthreads();

    // ---- GEMM2: logits = hid @ W2 + b2 ----
    float a2[4][8];
    #pragma unroll
    for (int j = 0; j < 8; ++j) {
        const float bj = b2[8 * cg + j];
        #pragma unroll
        for (int r = 0; r < 4; ++r) a2[r][j] = bj;
    }
    for (int kc = 0; kc < DR; kc += 32) {
        for (int idx = t; idx < 768; idx += 192) {
            const int k = idx / 24, cq = idx % 24;
            *(float4*)&wc[k][4 * cq] = *(const float4*)(W2 + (size_t)(kc + k) * DR + 4 * cq);
        }
        __syncthreads();
        #pragma unroll 4
        for (int k = 0; k < 32; ++k) {
            const uint2 hv = *(const uint2*)&hidT[kc + k][4 * rg];
            const float4 w0 = *(const float4*)&wc[k][8 * cg];
            const float4 w1 = *(const float4*)&wc[k][8 * cg + 4];
            const float xr[4] = {bflo(hv.x), bfhi(hv.x), bflo(hv.y), bfhi(hv.y)};
            const float wr[8] = {w0.x, w0.y, w0.z, w0.w, w1.x, w1.y, w1.z, w1.w};
            #pragma unroll
            for (int r = 0; r < 4; ++r)
                #pragma unroll
                for (int j = 0; j < 8; ++j) a2[r][j] += xr[r] * wr[j];
        }
        __syncthreads();
    }
    // logits -> mv (bf16)
    #pragma unroll
    for (int r = 0; r < 4; ++r) {
        unsigned p[4];
        #pragma unroll
        for (int jj = 0; jj < 4; ++jj)
            p[jj] = (unsigned)f2bf(a2[r][2 * jj]) | ((unsigned)f2bf(a2[r][2 * jj + 1]) << 16);
        *(uint2*)&mv[4 * rg + r][8 * cg]     = make_uint2(p[0], p[1]);
        *(uint2*)&mv[4 * rg + r][8 * cg + 4] = make_uint2(p[2], p[3]);
    }
    __syncthreads();

    // ---- softmax over k (stride 6 in cols), write mix bf16 [row][h][16k] ----
    for (int task = t; task < 384; task += 192) {
        const int r = task / 6, h = task % 6;
        float lg[KK];
        float mx = -1e30f;
        #pragma unroll
        for (int k = 0; k < KK; ++k) {
            lg[k] = __uint_as_float((unsigned)mv[r][6 * k + h] << 16);
            mx = fmaxf(mx, lg[k]);
        }
        float s = 0.f;
        #pragma unroll
        for (int k = 0; k < KK; ++k) { lg[k] = __expf(lg[k] - mx); s += lg[k]; }
        const float inv = 1.0f / s;
        unsigned o[8];
        #pragma unroll
        for (int jj = 0; jj < 8; ++jj)
            o[jj] = (unsigned)f2bf(lg[2 * jj] * inv) | ((unsigned)f2bf(lg[2 * jj + 1] * inv) << 16);
        unsigned* op = (unsigned*)(mix_out + ((size_t)(row0 + r) * HH + h) * KK);
        *(uint4*)op       = make_uint4(o[0], o[1], o[2], o[3]);
        *(uint4*)(op + 4) = make_uint4(o[4], o[5], o[6], o[7]);
    }
}

// ---------------------------------------------------------------------------
// Stage 2: out[b,m,h,c] = sum_n ( sum_k mix[b,n,h,k]*wb[k,n,m] ) * x[b,n,h*64+c]
// Grid 896 (b = bid&127 -> all 7 m-tiles of b on one XCD). 192 thr = 3 waves,
// 2 heads per wave (32 lanes/head), reg tile 7m x 8c. TN=14, MT=28.
// ---------------------------------------------------------------------------
__global__ __launch_bounds__(192, 4) void mix_kernel(
    const float* __restrict__ x,  const unsigned short* __restrict__ mixb,
    const float* __restrict__ wb, float* __restrict__ out)
{
    __shared__ float xs[14][CDIM];                 // 21504 B
    __shared__ unsigned short msb[14][HH][KK];     // 2688 B  [n][h][k] bf16
    __shared__ float As[28][7][16];                // 12544 B (h padded 6->7, n 14->16)

    const int t   = threadIdx.x;
    const int bid = blockIdx.x;
    const int b   = bid & 127;
    const int m0  = (bid >> 7) * 28;
    const int h   = t >> 5;          // 0..5 (two heads per wave)
    const int lan = t & 31;
    const int mg  = lan >> 3;        // 0..3 -> m = mg + 4i
    const int cg  = lan & 7;         // 0..7 -> c = 8*cg
    const int cbase = h * HD + 8 * cg;

    float acc[7][8];
    #pragma unroll
    for (int i = 0; i < 7; ++i)
        #pragma unroll
        for (int j = 0; j < 8; ++j) acc[i][j] = 0.f;

    for (int n0 = 0; n0 < NN; n0 += 14) {
        __syncthreads();
        // stage x tile (14 rows): 1344 float4, exactly 7 per thread
        {
            const float4* xg = (const float4*)(x + ((size_t)b * NN + n0) * CDIM);
            float4* xs4 = (float4*)&xs[0][0];
            #pragma unroll
            for (int i = 0; i < 7; ++i) xs4[t + 192 * i] = xg[t + 192 * i];
        }
        // stage mix tile: 14 rows x 96 bf16 = 672 uints  (FIX: was 336)
        {
            const unsigned* mgp = (const unsigned*)(mixb + ((size_t)b * NN + n0) * DR);
            unsigned* msu = (unsigned*)&msb[0][0][0];
            for (int idx = t; idx < 672; idx += 192) msu[idx] = mgp[idx];
        }
        __syncthreads();

        // A-form: As[m][h][n] = sum_k mix[n][h][k] * wb[k][n][m], m-pairs
        for (int task = t; task < 196; task += 192) {
            const int nl = task / 14, mlp = task % 14;
            const int n = n0 + nl, m = m0 + 2 * mlp;
            float2 wv[KK];
            #pragma unroll
            for (int k = 0; k < KK; ++k)
                wv[k] = *(const float2*)(wb + ((size_t)k * NN + n) * NN + m);
            #pragma unroll
            for (int hh = 0; hh < HH; ++hh) {
                const uint4 u = *(const uint4*)&msb[nl][hh][0];
                const uint4 v = *(const uint4*)&msb[nl][hh][8];
                const unsigned uu[8] = {u.x, u.y, u.z, u.w, v.x, v.y, v.z, v.w};
                float a0 = 0.f, a1 = 0.f;
                #pragma unroll
                for (int p = 0; p < 8; ++p) {
                    const float f0 = bflo(uu[p]), f1 = bfhi(uu[p]);
                    a0 += f0 * wv[2 * p].x;     a1 += f0 * wv[2 * p].y;
                    a0 += f1 * wv[2 * p + 1].x; a1 += f1 * wv[2 * p + 1].y;
                }
                As[2 * mlp][hh][nl]     = a0;
                As[2 * mlp + 1][hh][nl] = a1;
            }
        }
        __syncthreads();

        // main FMA: 3 groups of 4 n + tail of 2 n
        #pragma unroll
        for (int nq = 0; nq < 3; ++nq) {
            float4 A[7];
            #pragma unroll
            for (int i = 0; i < 7; ++i) A[i] = *(const float4*)&As[mg + 4 * i][h][4 * nq];
            #pragma unroll
            for (int j = 0; j < 4; ++j) {
                const float4 X0 = *(const float4*)&xs[4 * nq + j][cbase];
                const float4 X1 = *(const float4*)&xs[4 * nq + j][cbase + 4];
                #pragma unroll
                for (int i = 0; i < 7; ++i) {
                    const float a = (j == 0) ? A[i].x : (j == 1) ? A[i].y : (j == 2) ? A[i].z : A[i].w;
                    acc[i][0] += a * X0.x; acc[i][1] += a * X0.y;
                    acc[i][2] += a * X0.z; acc[i][3] += a * X0.w;
                    acc[i][4] += a * X1.x; acc[i][5] += a * X1.y;
                    acc[i][6] += a * X1.z; acc[i][7] += a * X1.w;
                }
            }
        }
        {   // tail: n = 12, 13
            float2 A2[7];
            #pragma unroll
            for (int i = 0; i < 7; ++i) A2[i] = *(const float2*)&As[mg + 4 * i][h][12];
            #pragma unroll
            for (int j = 0; j < 2; ++j) {
                const float4 X0 = *(const float4*)&xs[12 + j][cbase];
                const float4 X1 = *(const float4*)&xs[12 + j][cbase + 4];
                #pragma unroll
                for (int i = 0; i < 7; ++i) {
                    const float a = j ? A2[i].y : A2[i].x;
                    acc[i][0] += a * X0.x; acc[i][1] += a * X0.y;
                    acc[i][2] += a * X0.z; acc[i][3] += a * X0.w;
                    acc[i][4] += a * X1.x; acc[i][5] += a * X1.y;
                    acc[i][6] += a * X1.z; acc[i][7] += a * X1.w;
                }
            }
        }
    }

    // epilogue
    #pragma unroll
    for (int i = 0; i < 7; ++i) {
        float* op = out + ((size_t)b * NN + m0 + mg + 4 * i) * CDIM + cbase;
        *(float4*)op       = make_float4(acc[i][0], acc[i][1], acc[i][2], acc[i][3]);
        *(float4*)(op + 4) = make_float4(acc[i][4], acc[i][5], acc[i][6], acc[i][7]);
    }
}

extern "C" void kernel_launch(void* const* d_in, const int* in_sizes, int n_in,
                              void* d_out, int out_size, void* d_ws, size_t ws_size,
                              hipStream_t stream) {
    (void)in_sizes; (void)n_in; (void)out_size; (void)ws_size;
    const float* x  = (const float*)d_in[0];
    const float* W1 = (const float*)d_in[1];
    const float* b1 = (const float*)d_in[2];
    const float* W2 = (const float*)d_in[3];
    const float* b2 = (const float*)d_in[4];
    const float* wb = (const float*)d_in[5];
    float* out = (float*)d_out;
    unsigned short* mixbuf = (unsigned short*)d_ws;   // bf16 [B*N][H][K] = 4.8 MB

    adapter_kernel<<<(BB * NN) / 64, 192, 0, stream>>>(x, W1, b1, W2, b2, mixbuf);
    mix_kernel<<<(NN / 28) * BB, 192, 0, stream>>>(x, mixbuf, wb, out);
}

// Round 5
// 254.804 us; speedup vs baseline: 2.5290x; 1.2178x over previous
//
#include <hip/hip_runtime.h>
#include <math.h>

// Problem constants (AdaSpatialMLP): B=128, N=196, DIM=384, K=16, H=6, R=4
#define BB  128
#define NN  196
#define CDIM 384
#define KK  16
#define HH  6
#define DR  96    // DIM/R
#define HD  64    // DIM/H

typedef __attribute__((ext_vector_type(8))) short bf16x8;
typedef __attribute__((ext_vector_type(4))) float f32x4;

__device__ __forceinline__ unsigned short f2bf(float f) {
    unsigned u = __float_as_uint(f);
    u += 0x7FFFu + ((u >> 16) & 1u);   // RNE
    return (unsigned short)(u >> 16);
}
__device__ __forceinline__ unsigned pk2bf(float lo, float hi) {
    return (unsigned)f2bf(lo) | ((unsigned)f2bf(hi) << 16);
}
__device__ __forceinline__ float bflo(unsigned u) { return __uint_as_float(u << 16); }
__device__ __forceinline__ float bfhi(unsigned u) { return __uint_as_float(u & 0xFFFF0000u); }

// ---------------------------------------------------------------------------
// Stage 1 (unchanged from round 4): mix[b,n,h,k] (bf16) = softmax_k(MLP(x))
// ---------------------------------------------------------------------------
__global__ __launch_bounds__(192, 4) void adapter_kernel(
    const float* __restrict__ x,  const float* __restrict__ W1,
    const float* __restrict__ b1, const float* __restrict__ W2,
    const float* __restrict__ b2, unsigned short* __restrict__ mix_out)
{
    __shared__ float xsT[32][68];
    __shared__ float wc[32][100];
    __shared__ unsigned short hidT[96][68];
    __shared__ unsigned short mv[64][100];

    const int t = threadIdx.x;
    const int row0 = blockIdx.x * 64;
    const int rg = t / 12;
    const int cg = t % 12;

    float acc[4][8];
    #pragma unroll
    for (int j = 0; j < 8; ++j) {
        const float bj = b1[8 * cg + j];
        #pragma unroll
        for (int r = 0; r < 4; ++r) acc[r][j] = bj;
    }
    for (int kc = 0; kc < CDIM; kc += 32) {
        for (int idx = t; idx < 512; idx += 192) {
            const int row = idx >> 3, kq = idx & 7;
            const float4 v = *(const float4*)(x + (size_t)(row0 + row) * CDIM + kc + 4 * kq);
            xsT[4 * kq + 0][row] = v.x; xsT[4 * kq + 1][row] = v.y;
            xsT[4 * kq + 2][row] = v.z; xsT[4 * kq + 3][row] = v.w;
        }
        for (int idx = t; idx < 768; idx += 192) {
            const int k = idx / 24, cq = idx % 24;
            *(float4*)&wc[k][4 * cq] = *(const float4*)(W1 + (size_t)(kc + k) * DR + 4 * cq);
        }
        __syncthreads();
        #pragma unroll 4
        for (int k = 0; k < 32; ++k) {
            const float4 xv = *(const float4*)&xsT[k][4 * rg];
            const float4 w0 = *(const float4*)&wc[k][8 * cg];
            const float4 w1 = *(const float4*)&wc[k][8 * cg + 4];
            const float xr[4] = {xv.x, xv.y, xv.z, xv.w};
            const float wr[8] = {w0.x, w0.y, w0.z, w0.w, w1.x, w1.y, w1.z, w1.w};
            #pragma unroll
            for (int r = 0; r < 4; ++r)
                #pragma unroll
                for (int j = 0; j < 8; ++j) acc[r][j] += xr[r] * wr[j];
        }
        __syncthreads();
    }
    #pragma unroll
    for (int j = 0; j < 8; ++j) {
        unsigned short g[4];
        #pragma unroll
        for (int r = 0; r < 4; ++r) {
            const float v = acc[r][j];
            g[r] = f2bf(0.5f * v * (1.0f + erff(v * 0.70710678118654752f)));
        }
        *(unsigned*)&hidT[8 * cg + j][4 * rg]     = (unsigned)g[0] | ((unsigned)g[1] << 16);
        *(unsigned*)&hidT[8 * cg + j][4 * rg + 2] = (unsigned)g[2] | ((unsigned)g[3] << 16);
    }
    __syncthreads();

    float a2[4][8];
    #pragma unroll
    for (int j = 0; j < 8; ++j) {
        const float bj = b2[8 * cg + j];
        #pragma unroll
        for (int r = 0; r < 4; ++r) a2[r][j] = bj;
    }
    for (int kc = 0; kc < DR; kc += 32) {
        for (int idx = t; idx < 768; idx += 192) {
            const int k = idx / 24, cq = idx % 24;
            *(float4*)&wc[k][4 * cq] = *(const float4*)(W2 + (size_t)(kc + k) * DR + 4 * cq);
        }
        __syncthreads();
        #pragma unroll 4
        for (int k = 0; k < 32; ++k) {
            const uint2 hv = *(const uint2*)&hidT[kc + k][4 * rg];
            const float4 w0 = *(const float4*)&wc[k][8 * cg];
            const float4 w1 = *(const float4*)&wc[k][8 * cg + 4];
            const float xr[4] = {bflo(hv.x), bfhi(hv.x), bflo(hv.y), bfhi(hv.y)};
            const float wr[8] = {w0.x, w0.y, w0.z, w0.w, w1.x, w1.y, w1.z, w1.w};
            #pragma unroll
            for (int r = 0; r < 4; ++r)
                #pragma unroll
                for (int j = 0; j < 8; ++j) a2[r][j] += xr[r] * wr[j];
        }
        __syncthreads();
    }
    #pragma unroll
    for (int r = 0; r < 4; ++r) {
        unsigned p[4];
        #pragma unroll
        for (int jj = 0; jj < 4; ++jj)
            p[jj] = pk2bf(a2[r][2 * jj], a2[r][2 * jj + 1]);
        *(uint2*)&mv[4 * rg + r][8 * cg]     = make_uint2(p[0], p[1]);
        *(uint2*)&mv[4 * rg + r][8 * cg + 4] = make_uint2(p[2], p[3]);
    }
    __syncthreads();

    for (int task = t; task < 384; task += 192) {
        const int r = task / 6, h = task % 6;
        float lg[KK];
        float mx = -1e30f;
        #pragma unroll
        for (int k = 0; k < KK; ++k) {
            lg[k] = __uint_as_float((unsigned)mv[r][6 * k + h] << 16);
            mx = fmaxf(mx, lg[k]);
        }
        float s = 0.f;
        #pragma unroll
        for (int k = 0; k < KK; ++k) { lg[k] = __expf(lg[k] - mx); s += lg[k]; }
        const float inv = 1.0f / s;
        unsigned o[8];
        #pragma unroll
        for (int jj = 0; jj < 8; ++jj)
            o[jj] = pk2bf(lg[2 * jj] * inv, lg[2 * jj + 1] * inv);
        unsigned* op = (unsigned*)(mix_out + ((size_t)(row0 + r) * HH + h) * KK);
        *(uint4*)op       = make_uint4(o[0], o[1], o[2], o[3]);
        *(uint4*)(op + 4) = make_uint4(o[4], o[5], o[6], o[7]);
    }
}

// ---------------------------------------------------------------------------
// Stage 2, MFMA: per (b, m-quarter): out_h[m,c] = sum_n A_h^T[m,n] * x_h[n,c]
// 384 thr = 6 waves, wave = head. K-loop over 7 chunks of 32 n.
// A-frag: lane holds A[m = L&15][n = (L>>4)*8+j]  -> Asb[h][m][n], n-contig.
// B-frag: lane holds B[n = (L>>4)*8+j][c = L&15]  -> xT[c][n], n-contig.
// C/D: col c = L&15, row m = (L>>4)*4 + reg (m89-verified).
// Pitch 40 bf16 (80 B): 16B-aligned rows, bank-starts 20m mod 32 spaced.
// ---------------------------------------------------------------------------
__global__ __launch_bounds__(384, 3) void mix_mfma_kernel(
    const float* __restrict__ x,  const unsigned short* __restrict__ mixb,
    const float* __restrict__ wb, float* __restrict__ out)
{
    __shared__ unsigned short xT[CDIM][40];    // [c][n] bf16, 30720 B
    __shared__ unsigned short Asb[HH][64][40]; // [h][m][n] bf16, 30720 B
    __shared__ unsigned short msc[32][96];     // [n][h*16+k] bf16, 6144 B

    const int t   = threadIdx.x;
    const int bid = blockIdx.x;
    const int q   = bid & 3;          // m-quarter: same-q blocks share an XCD
    const int b   = bid >> 2;
    const int m0  = q * 52;
    const int qvalid = (q == 3) ? 40 : 52;
    const int h   = t >> 6;           // wave id == head
    const int lane = t & 63;
    const int l15 = lane & 15;
    const int lq  = lane >> 4;

    f32x4 acc[4][4];
    #pragma unroll
    for (int mt = 0; mt < 4; ++mt)
        #pragma unroll
        for (int ct = 0; ct < 4; ++ct) acc[mt][ct] = (f32x4){0.f, 0.f, 0.f, 0.f};

    for (int nc = 0; nc < 7; ++nc) {
        const int n0 = nc * 32;
        __syncthreads();   // previous chunk's MFMA reads done

        // ---- stage x -> xT bf16 transposed (n-pairs packed as b32) ----
        #pragma unroll
        for (int it = 0; it < 4; ++it) {
            const int task = t + 384 * it;      // 0..1535
            const int p  = task / 96;           // n-pair 0..15
            const int cq = task - p * 96;       // c-quad 0..95
            const int n  = n0 + 2 * p;
            float4 va = make_float4(0.f, 0.f, 0.f, 0.f);
            float4 vb = make_float4(0.f, 0.f, 0.f, 0.f);
            if (n < NN)     va = *(const float4*)(x + ((size_t)b * NN + n) * CDIM + 4 * cq);
            if (n + 1 < NN) vb = *(const float4*)(x + ((size_t)b * NN + n + 1) * CDIM + 4 * cq);
            *(unsigned*)&xT[4 * cq + 0][2 * p] = pk2bf(va.x, vb.x);
            *(unsigned*)&xT[4 * cq + 1][2 * p] = pk2bf(va.y, vb.y);
            *(unsigned*)&xT[4 * cq + 2][2 * p] = pk2bf(va.z, vb.z);
            *(unsigned*)&xT[4 * cq + 3][2 * p] = pk2bf(va.w, vb.w);
        }
        // ---- stage mix chunk (raw copy, zero-fill n>=196) ----
        #pragma unroll
        for (int it = 0; it < 4; ++it) {
            const int idx = t + 384 * it;       // 0..1535 u32
            const int nl = idx / 48, cw = idx - nl * 48;
            unsigned v = 0u;
            if (n0 + nl < NN)
                v = *(const unsigned*)(mixb + ((size_t)b * NN + n0 + nl) * DR + 2 * cw);
            *(unsigned*)&msc[nl][2 * cw] = v;
        }
        __syncthreads();

        // ---- A-form: Asb[h][m][n] = sum_k mix[n][h][k] * wb[k][n][m0+m] ----
        for (int task = t; task < 832; task += 384) {
            const int nl = task / 26;
            const int mp = task - nl * 26;
            const int n  = n0 + nl;
            const int ms = 2 * mp;
            if (n < NN && ms < qvalid) {
                const int m = m0 + ms;
                float2 wv[KK];
                #pragma unroll
                for (int k = 0; k < KK; ++k)
                    wv[k] = *(const float2*)(wb + ((size_t)k * NN + n) * NN + m);
                #pragma unroll
                for (int hh = 0; hh < HH; ++hh) {
                    const uint4 u = *(const uint4*)&msc[nl][hh * 16];
                    const uint4 v = *(const uint4*)&msc[nl][hh * 16 + 8];
                    const unsigned uu[8] = {u.x, u.y, u.z, u.w, v.x, v.y, v.z, v.w};
                    float a0 = 0.f, a1 = 0.f;
                    #pragma unroll
                    for (int p = 0; p < 8; ++p) {
                        const float f0 = bflo(uu[p]), f1 = bfhi(uu[p]);
                        a0 += f0 * wv[2 * p].x;     a1 += f0 * wv[2 * p].y;
                        a0 += f1 * wv[2 * p + 1].x; a1 += f1 * wv[2 * p + 1].y;
                    }
                    Asb[hh][ms][nl]     = f2bf(a0);
                    Asb[hh][ms + 1][nl] = f2bf(a1);
                }
            } else {
                #pragma unroll
                for (int hh = 0; hh < HH; ++hh) {
                    Asb[hh][ms][nl] = 0; Asb[hh][ms + 1][nl] = 0;
                }
            }
        }
        __syncthreads();

        // ---- MFMA: 4 m-tiles x 4 c-tiles, K-chunk = 32 ----
        bf16x8 afr[4], bfr[4];
        #pragma unroll
        for (int mt = 0; mt < 4; ++mt)
            afr[mt] = *(const bf16x8*)&Asb[h][mt * 16 + l15][8 * lq];
        #pragma unroll
        for (int ct = 0; ct < 4; ++ct)
            bfr[ct] = *(const bf16x8*)&xT[h * HD + ct * 16 + l15][8 * lq];
        #pragma unroll
        for (int mt = 0; mt < 4; ++mt)
            #pragma unroll
            for (int ct = 0; ct < 4; ++ct)
                acc[mt][ct] = __builtin_amdgcn_mfma_f32_16x16x32_bf16(
                    afr[mt], bfr[ct], acc[mt][ct], 0, 0, 0);
    }

    // ---- epilogue: C/D layout col=l15, row=lq*4+r ----
    #pragma unroll
    for (int mt = 0; mt < 4; ++mt) {
        #pragma unroll
        for (int r = 0; r < 4; ++r) {
            const int ms = mt * 16 + lq * 4 + r;
            if (ms < qvalid) {
                float* op = out + ((size_t)b * NN + m0 + ms) * CDIM + h * HD + l15;
                #pragma unroll
                for (int ct = 0; ct < 4; ++ct)
                    op[ct * 16] = acc[mt][ct][r];
            }
        }
    }
}

extern "C" void kernel_launch(void* const* d_in, const int* in_sizes, int n_in,
                              void* d_out, int out_size, void* d_ws, size_t ws_size,
                              hipStream_t stream) {
    (void)in_sizes; (void)n_in; (void)out_size; (void)ws_size;
    const float* x  = (const float*)d_in[0];
    const float* W1 = (const float*)d_in[1];
    const float* b1 = (const float*)d_in[2];
    const float* W2 = (const float*)d_in[3];
    const float* b2 = (const float*)d_in[4];
    const float* wb = (const float*)d_in[5];
    float* out = (float*)d_out;
    unsigned short* mixbuf = (unsigned short*)d_ws;   // bf16 [B*N][H][K] = 4.8 MB

    adapter_kernel<<<(BB * NN) / 64, 192, 0, stream>>>(x, W1, b1, W2, b2, mixbuf);
    mix_mfma_kernel<<<4 * BB, 384, 0, stream>>>(x, mixbuf, wb, out);
}

// Round 6
// 223.855 us; speedup vs baseline: 2.8786x; 1.1383x over previous
//
#include <hip/hip_runtime.h>
#include <math.h>

// Problem constants (AdaSpatialMLP): B=128, N=196, DIM=384, K=16, H=6, R=4
#define BB  128
#define NN  196
#define CDIM 384
#define KK  16
#define HH  6
#define DR  96    // DIM/R
#define HD  64    // DIM/H

typedef __attribute__((ext_vector_type(8))) short bf16x8;
typedef __attribute__((ext_vector_type(4))) float f32x4;

__device__ __forceinline__ unsigned short f2bf(float f) {
    unsigned u = __float_as_uint(f);
    u += 0x7FFFu + ((u >> 16) & 1u);   // RNE
    return (unsigned short)(u >> 16);
}
__device__ __forceinline__ unsigned pk2bf(float lo, float hi) {
    return (unsigned)f2bf(lo) | ((unsigned)f2bf(hi) << 16);
}
__device__ __forceinline__ float bflo(unsigned u) { return __uint_as_float(u << 16); }
__device__ __forceinline__ float bfhi(unsigned u) { return __uint_as_float(u & 0xFFFF0000u); }

union AFrag { unsigned u[4]; bf16x8 f; };

// ---------------------------------------------------------------------------
// Prep: W1T[c][k] bf16 (96x384), W2T[c][k] bf16 (96x96) — one-time transpose
// so adapter B-frags load k-contiguous straight from global (L1/L2-hot).
// ---------------------------------------------------------------------------
__global__ __launch_bounds__(128) void prep_kernel(
    const float* __restrict__ W1, const float* __restrict__ W2,
    unsigned short* __restrict__ W1T, unsigned short* __restrict__ W2T)
{
    const int c = blockIdx.x;     // 0..95
    const int t = threadIdx.x;    // 0..127
    for (int k = t; k < CDIM; k += 128)
        W1T[(size_t)c * CDIM + k] = f2bf(W1[(size_t)k * DR + c]);
    if (t < DR)
        W2T[(size_t)c * DR + t] = f2bf(W2[(size_t)t * DR + c]);
}

// ---------------------------------------------------------------------------
// Stage 1 (MFMA): mix[row][h][k] bf16 = softmax_k( gelu(x@W1+b1) @ W2 + b2 )
// 784 blocks x 256 thr (4 waves = 2 row-halves x 2 col-halves), 32 rows/block.
// GEMM1: A-frags packed directly from global fp32 x (lane layout == row-major
// x), B-frags from global W1T bf16. No LDS, no barriers. GEMM2 via hid in LDS.
// ---------------------------------------------------------------------------
__global__ __launch_bounds__(256, 3) void adapter_kernel(
    const float* __restrict__ x,   const unsigned short* __restrict__ W1T,
    const float* __restrict__ b1,  const unsigned short* __restrict__ W2T,
    const float* __restrict__ b2,  unsigned short* __restrict__ mix_out)
{
    __shared__ unsigned short hidb[32][104];   // bf16, pitch 104 (208 B, 16B-mult)

    const int t    = threadIdx.x;
    const int w    = t >> 6;        // wave 0..3
    const int wm   = w & 1;         // row half
    const int wc   = w >> 1;        // col half
    const int lane = t & 63;
    const int l15  = lane & 15;
    const int lq   = lane >> 4;
    const int row0 = blockIdx.x * 32;

    // ---- GEMM1: hid = gelu(x @ W1 + b1), rows wm*16+l15, cols wc*48+ct*16+l15
    f32x4 acc[3];
    #pragma unroll
    for (int ct = 0; ct < 3; ++ct) {
        const float bj = b1[wc * 48 + ct * 16 + l15];
        acc[ct] = (f32x4){bj, bj, bj, bj};
    }
    const float* xrow = x + (size_t)(row0 + wm * 16 + l15) * CDIM;
    for (int kc = 0; kc < CDIM; kc += 32) {
        const float4 u = *(const float4*)(xrow + kc + 8 * lq);
        const float4 v = *(const float4*)(xrow + kc + 8 * lq + 4);
        AFrag af;
        af.u[0] = pk2bf(u.x, u.y); af.u[1] = pk2bf(u.z, u.w);
        af.u[2] = pk2bf(v.x, v.y); af.u[3] = pk2bf(v.z, v.w);
        #pragma unroll
        for (int ct = 0; ct < 3; ++ct) {
            const bf16x8 bf = *(const bf16x8*)(W1T + (size_t)(wc * 48 + ct * 16 + l15) * CDIM + kc + 8 * lq);
            acc[ct] = __builtin_amdgcn_mfma_f32_16x16x32_bf16(af.f, bf, acc[ct], 0, 0, 0);
        }
    }
    // GELU (exact erf) -> hidb (C-layout: col=l15, row=lq*4+r)
    #pragma unroll
    for (int ct = 0; ct < 3; ++ct)
        #pragma unroll
        for (int r = 0; r < 4; ++r) {
            const float vv = acc[ct][r];
            hidb[wm * 16 + lq * 4 + r][wc * 48 + ct * 16 + l15] =
                f2bf(0.5f * vv * (1.0f + erff(vv * 0.70710678118654752f)));
        }
    __syncthreads();

    // ---- GEMM2: logits = hid @ W2 + b2 ----
    f32x4 acc2[3];
    #pragma unroll
    for (int ct = 0; ct < 3; ++ct) {
        const float bj = b2[wc * 48 + ct * 16 + l15];
        acc2[ct] = (f32x4){bj, bj, bj, bj};
    }
    #pragma unroll
    for (int kc = 0; kc < DR; kc += 32) {
        const bf16x8 af = *(const bf16x8*)&hidb[wm * 16 + l15][kc + 8 * lq];
        #pragma unroll
        for (int ct = 0; ct < 3; ++ct) {
            const bf16x8 bf = *(const bf16x8*)(W2T + (size_t)(wc * 48 + ct * 16 + l15) * DR + kc + 8 * lq);
            acc2[ct] = __builtin_amdgcn_mfma_f32_16x16x32_bf16(af, bf, acc2[ct], 0, 0, 0);
        }
    }
    __syncthreads();   // all hidb reads done; reuse as logits buffer

    #pragma unroll
    for (int ct = 0; ct < 3; ++ct)
        #pragma unroll
        for (int r = 0; r < 4; ++r)
            hidb[wm * 16 + lq * 4 + r][wc * 48 + ct * 16 + l15] = f2bf(acc2[ct][r]);
    __syncthreads();

    // ---- softmax over k (col = k*6+h), write mix bf16 [row][h][16k] ----
    if (t < 192) {
        const int r = t / 6, h = t % 6;
        float lg[KK];
        float mx = -1e30f;
        #pragma unroll
        for (int k = 0; k < KK; ++k) {
            lg[k] = __uint_as_float((unsigned)hidb[r][6 * k + h] << 16);
            mx = fmaxf(mx, lg[k]);
        }
        float s = 0.f;
        #pragma unroll
        for (int k = 0; k < KK; ++k) { lg[k] = __expf(lg[k] - mx); s += lg[k]; }
        const float inv = 1.0f / s;
        unsigned o[8];
        #pragma unroll
        for (int jj = 0; jj < 8; ++jj)
            o[jj] = pk2bf(lg[2 * jj] * inv, lg[2 * jj + 1] * inv);
        unsigned* op = (unsigned*)(mix_out + ((size_t)(row0 + r) * HH + h) * KK);
        *(uint4*)op       = make_uint4(o[0], o[1], o[2], o[3]);
        *(uint4*)(op + 4) = make_uint4(o[4], o[5], o[6], o[7]);
    }
}

// ---------------------------------------------------------------------------
// Stage 2, MFMA: per (b, m-quarter): out_h[m,c] = sum_n A_h^T[m,n] * x_h[n,c]
// 384 thr = 6 waves, wave = head. K-loop over 7 chunks of 32 n.
// xT staging remapped (p = task&15) so writes are bank-conflict-free.
// ---------------------------------------------------------------------------
__global__ __launch_bounds__(384, 3) void mix_mfma_kernel(
    const float* __restrict__ x,  const unsigned short* __restrict__ mixb,
    const float* __restrict__ wb, float* __restrict__ out)
{
    __shared__ unsigned short xT[CDIM][40];    // [c][n] bf16, 30720 B
    __shared__ unsigned short Asb[HH][64][40]; // [h][m][n] bf16, 30720 B
    __shared__ unsigned short msc[32][96];     // [n][h*16+k] bf16, 6144 B

    const int t   = threadIdx.x;
    const int bid = blockIdx.x;
    const int q   = bid & 3;          // m-quarter: same-q blocks share an XCD
    const int b   = bid >> 2;
    const int m0  = q * 52;
    const int qvalid = (q == 3) ? 40 : 52;
    const int h   = t >> 6;           // wave id == head
    const int lane = t & 63;
    const int l15 = lane & 15;
    const int lq  = lane >> 4;

    f32x4 acc[4][4];
    #pragma unroll
    for (int mt = 0; mt < 4; ++mt)
        #pragma unroll
        for (int ct = 0; ct < 4; ++ct) acc[mt][ct] = (f32x4){0.f, 0.f, 0.f, 0.f};

    for (int nc = 0; nc < 7; ++nc) {
        const int n0 = nc * 32;
        __syncthreads();   // previous chunk's MFMA reads done

        // ---- stage x -> xT bf16 transposed. Remapped: adjacent lanes vary
        // n-pair p -> LDS write banks +1 per lane (conflict-free).
        #pragma unroll
        for (int it = 0; it < 4; ++it) {
            const int task = t + 384 * it;      // 0..1535
            const int p  = task & 15;           // n-pair 0..15
            const int cq = task >> 4;           // c-quad 0..95
            const int n  = n0 + 2 * p;
            float4 va = make_float4(0.f, 0.f, 0.f, 0.f);
            float4 vb = make_float4(0.f, 0.f, 0.f, 0.f);
            if (n < NN)     va = *(const float4*)(x + ((size_t)b * NN + n) * CDIM + 4 * cq);
            if (n + 1 < NN) vb = *(const float4*)(x + ((size_t)b * NN + n + 1) * CDIM + 4 * cq);
            *(unsigned*)&xT[4 * cq + 0][2 * p] = pk2bf(va.x, vb.x);
            *(unsigned*)&xT[4 * cq + 1][2 * p] = pk2bf(va.y, vb.y);
            *(unsigned*)&xT[4 * cq + 2][2 * p] = pk2bf(va.z, vb.z);
            *(unsigned*)&xT[4 * cq + 3][2 * p] = pk2bf(va.w, vb.w);
        }
        // ---- stage mix chunk (raw copy, zero-fill n>=196) ----
        #pragma unroll
        for (int it = 0; it < 4; ++it) {
            const int idx = t + 384 * it;       // 0..1535 u32
            const int nl = idx / 48, cw = idx - nl * 48;
            unsigned v = 0u;
            if (n0 + nl < NN)
                v = *(const unsigned*)(mixb + ((size_t)b * NN + n0 + nl) * DR + 2 * cw);
            *(unsigned*)&msc[nl][2 * cw] = v;
        }
        __syncthreads();

        // ---- A-form: Asb[h][m][n] = sum_k mix[n][h][k] * wb[k][n][m0+m] ----
        for (int task = t; task < 832; task += 384) {
            const int nl = task / 26;
            const int mp = task - nl * 26;
            const int n  = n0 + nl;
            const int ms = 2 * mp;
            if (n < NN && ms < qvalid) {
                const int m = m0 + ms;
                float2 wv[KK];
                #pragma unroll
                for (int k = 0; k < KK; ++k)
                    wv[k] = *(const float2*)(wb + ((size_t)k * NN + n) * NN + m);
                #pragma unroll
                for (int hh = 0; hh < HH; ++hh) {
                    const uint4 u = *(const uint4*)&msc[nl][hh * 16];
                    const uint4 v = *(const uint4*)&msc[nl][hh * 16 + 8];
                    const unsigned uu[8] = {u.x, u.y, u.z, u.w, v.x, v.y, v.z, v.w};
                    float a0 = 0.f, a1 = 0.f;
                    #pragma unroll
                    for (int p = 0; p < 8; ++p) {
                        const float f0 = bflo(uu[p]), f1 = bfhi(uu[p]);
                        a0 += f0 * wv[2 * p].x;     a1 += f0 * wv[2 * p].y;
                        a0 += f1 * wv[2 * p + 1].x; a1 += f1 * wv[2 * p + 1].y;
                    }
                    Asb[hh][ms][nl]     = f2bf(a0);
                    Asb[hh][ms + 1][nl] = f2bf(a1);
                }
            } else {
                #pragma unroll
                for (int hh = 0; hh < HH; ++hh) {
                    Asb[hh][ms][nl] = 0; Asb[hh][ms + 1][nl] = 0;
                }
            }
        }
        __syncthreads();

        // ---- MFMA: 4 m-tiles x 4 c-tiles, K-chunk = 32 ----
        bf16x8 afr[4], bfr[4];
        #pragma unroll
        for (int mt = 0; mt < 4; ++mt)
            afr[mt] = *(const bf16x8*)&Asb[h][mt * 16 + l15][8 * lq];
        #pragma unroll
        for (int ct = 0; ct < 4; ++ct)
            bfr[ct] = *(const bf16x8*)&xT[h * HD + ct * 16 + l15][8 * lq];
        #pragma unroll
        for (int mt = 0; mt < 4; ++mt)
            #pragma unroll
            for (int ct = 0; ct < 4; ++ct)
                acc[mt][ct] = __builtin_amdgcn_mfma_f32_16x16x32_bf16(
                    afr[mt], bfr[ct], acc[mt][ct], 0, 0, 0);
    }

    // ---- epilogue: C/D layout col=l15, row=lq*4+r ----
    #pragma unroll
    for (int mt = 0; mt < 4; ++mt) {
        #pragma unroll
        for (int r = 0; r < 4; ++r) {
            const int ms = mt * 16 + lq * 4 + r;
            if (ms < qvalid) {
                float* op = out + ((size_t)b * NN + m0 + ms) * CDIM + h * HD + l15;
                #pragma unroll
                for (int ct = 0; ct < 4; ++ct)
                    op[ct * 16] = acc[mt][ct][r];
            }
        }
    }
}

extern "C" void kernel_launch(void* const* d_in, const int* in_sizes, int n_in,
                              void* d_out, int out_size, void* d_ws, size_t ws_size,
                              hipStream_t stream) {
    (void)in_sizes; (void)n_in; (void)out_size; (void)ws_size;
    const float* x  = (const float*)d_in[0];
    const float* W1 = (const float*)d_in[1];
    const float* b1 = (const float*)d_in[2];
    const float* W2 = (const float*)d_in[3];
    const float* b2 = (const float*)d_in[4];
    const float* wb = (const float*)d_in[5];
    float* out = (float*)d_out;

    unsigned short* mixbuf = (unsigned short*)d_ws;              // 4,816,896 B
    unsigned short* w1t = (unsigned short*)((char*)d_ws + 4816896);   // 73,728 B
    unsigned short* w2t = (unsigned short*)((char*)d_ws + 4890624);   // 18,432 B

    prep_kernel<<<96, 128, 0, stream>>>(W1, W2, w1t, w2t);
    adapter_kernel<<<(BB * NN) / 32, 256, 0, stream>>>(x, w1t, b1, w2t, b2, mixbuf);
    mix_mfma_kernel<<<4 * BB, 384, 0, stream>>>(x, mixbuf, wb, out);
}